// Round 1
// baseline (335.290 us; speedup 1.0000x reference)
//
#include <hip/hip_runtime.h>

typedef _Float16 half2v __attribute__((ext_vector_type(2)));
typedef _Float16 half8  __attribute__((ext_vector_type(8)));
typedef float    f32x4  __attribute__((ext_vector_type(4)));

// ---------------- CSR build ----------------
__global__ void count_deg_k(const int* __restrict__ dst, int* __restrict__ deg, int E) {
  int t = blockIdx.x * 256 + threadIdx.x;
  if (t < E) atomicAdd(&deg[dst[t]], 1);
}

__global__ void scan_k(const int* __restrict__ deg, int* __restrict__ row_off, int N) {
  __shared__ int part[1024];
  int t = threadIdx.x;
  int CH = (N + 1023) >> 10;              // 49 for N=50000
  int b = t * CH, e = min(b + CH, N);
  int s = 0;
  for (int i = b; i < e; ++i) s += deg[i];
  part[t] = s;
  __syncthreads();
  for (int off = 1; off < 1024; off <<= 1) {
    int v = part[t];
    int a = (t >= off) ? part[t - off] : 0;
    __syncthreads();
    part[t] = v + a;
    __syncthreads();
  }
  int run = part[t] - s;                  // exclusive prefix of this chunk
  for (int i = b; i < e; ++i) { row_off[i] = run; run += deg[i]; }
  if (t == 1023) row_off[N] = part[1023];
}

__global__ void fill_k(const int* __restrict__ src, const int* __restrict__ dst,
                       const int* __restrict__ row_off, int* __restrict__ cur,
                       int* __restrict__ csr, int E) {
  int t = blockIdx.x * 256 + threadIdx.x;
  if (t < E) {
    int d = dst[t];
    int p = atomicAdd(&cur[d], 1);
    csr[row_off[d] + p] = src[t];
  }
}

// ---------------- embedding gather (fp32 emb -> f16 x) ----------------
__global__ void gather_k(const int* __restrict__ ent, const float* __restrict__ emb,
                         _Float16* __restrict__ X, int N) {
  int t = blockIdx.x * 256 + threadIdx.x;
  if (t >= N * 16) return;
  int node = t >> 4, g = t & 15;
  const float4* s = (const float4*)(emb + (long)ent[node] * 128 + g * 8);
  float4 a = s[0], b = s[1];
  half8 o;
  o[0] = (_Float16)a.x; o[1] = (_Float16)a.y; o[2] = (_Float16)a.z; o[3] = (_Float16)a.w;
  o[4] = (_Float16)b.x; o[5] = (_Float16)b.y; o[6] = (_Float16)b.z; o[7] = (_Float16)b.w;
  *(half8*)(X + (long)t * 8) = o;
}

// ---------------- weight pack into MFMA B-fragment order ----------------
// B[k][n]: lane holds B[kt*32 + (lane>>4)*8 + j][nt*16 + (lane&15)], j=0..7, 16B contiguous.
// k < 128 -> Wa[k][n], else Wb[k-128][n] (stacked [Wl;Wr] for the concat-GEMM).
__global__ void pack_k(const float* __restrict__ Wa, const float* __restrict__ Wb,
                       _Float16* __restrict__ out, int KT, int NT, int ncols) {
  int t = blockIdx.x * 256 + threadIdx.x;
  if (t >= KT * NT * 64) return;
  int lane = t & 63, tile = t >> 6;
  int nt = tile % NT, kt = tile / NT;
  int n  = nt * 16 + (lane & 15);
  int kb = kt * 32 + (lane >> 4) * 8;
  half8 o;
#pragma unroll
  for (int j = 0; j < 8; ++j) {
    int k = kb + j;
    float w = (k < 128) ? Wa[k * ncols + n] : Wb[(k - 128) * ncols + n];
    o[j] = (_Float16)w;
  }
  *(half8*)(out + (long)t * 8) = o;
}

// ---------------- mean aggregation via CSR gather (wave per node) ----------------
__global__ void agg_k(const _Float16* __restrict__ X, const int* __restrict__ row_off,
                      const int* __restrict__ csr, _Float16* __restrict__ A, int N) {
  int node = blockIdx.x * 4 + (threadIdx.x >> 6);
  if (node >= N) return;
  int lane = threadIdx.x & 63;          // lane covers dims 2*lane, 2*lane+1
  int beg = row_off[node], end = row_off[node + 1];
  float ax = 0.f, ay = 0.f;
#pragma unroll 4
  for (int e = beg; e < end; ++e) {
    half2v v = *(const half2v*)(X + (long)csr[e] * 128 + lane * 2);
    ax += (float)v[0]; ay += (float)v[1];
  }
  float inv = 1.f / fmaxf((float)(end - beg), 1.f);
  half2v o; o[0] = (_Float16)(ax * inv); o[1] = (_Float16)(ay * inv);
  *(half2v*)(A + (long)node * 128 + lane * 2) = o;
}

// ---------------- fused concat-GEMM: Out = act([A1|A2] @ Bp + bias) ----------------
// Block = 4 waves, 64 rows. Wave: 16 rows x NT*16 cols, K = (KT1+KT2)*32.
// A-frag: lane holds A[row0 + (lane&15)][kt*32 + (lane>>4)*8 + j]  (one dwordx4)
// D-frag: col = lane&15, row = (lane>>4)*4 + reg                   (guide m89/m91)
template <int KT1, int KT2, int NT, bool RELU, bool OUTF32>
__global__ __launch_bounds__(256) void gemm_k(const _Float16* __restrict__ A1,
                                              const _Float16* __restrict__ A2,
                                              const _Float16* __restrict__ Bp,
                                              const float* __restrict__ bias,
                                              void* __restrict__ Outv, int M) {
  constexpr int KT = KT1 + KT2;
  constexpr int N  = NT * 16;
  int wave = threadIdx.x >> 6, lane = threadIdx.x & 63;
  int row0 = blockIdx.x * 64 + wave * 16;
  int m = lane & 15, quad = lane >> 4;
  int arow = row0 + m; if (arow > M - 1) arow = M - 1;   // clamp tail loads
  f32x4 acc[NT];
#pragma unroll
  for (int i = 0; i < NT; ++i) acc[i] = (f32x4){0.f, 0.f, 0.f, 0.f};
#pragma unroll
  for (int kt = 0; kt < KT; ++kt) {
    const _Float16* s = (kt < KT1) ? (A1 + (long)arow * (KT1 * 32) + kt * 32)
                                   : (A2 + (long)arow * (KT2 * 32) + (kt - KT1) * 32);
    half8 af = *(const half8*)(s + quad * 8);
#pragma unroll
    for (int nt = 0; nt < NT; ++nt) {
      half8 bf = *(const half8*)(Bp + ((long)(kt * NT + nt) * 64 + lane) * 8);
      acc[nt] = __builtin_amdgcn_mfma_f32_16x16x32_f16(af, bf, acc[nt], 0, 0, 0);
    }
  }
#pragma unroll
  for (int nt = 0; nt < NT; ++nt) {
    float bv = bias[nt * 16 + m];
#pragma unroll
    for (int r = 0; r < 4; ++r) {
      int orow = row0 + quad * 4 + r;
      if (orow < M) {
        float v = acc[nt][r] + bv;
        if (RELU) v = fmaxf(v, 0.f);
        long oi = (long)orow * N + nt * 16 + m;
        if (OUTF32) ((float*)Outv)[oi] = v;
        else        ((_Float16*)Outv)[oi] = (_Float16)v;
      }
    }
  }
}

extern "C" void kernel_launch(void* const* d_in, const int* in_sizes, int n_in,
                              void* d_out, int out_size, void* d_ws, size_t ws_size,
                              hipStream_t stream) {
  const int N = in_sizes[0];
  const int E = in_sizes[1] / 2;
  const int*   entity = (const int*)d_in[0];
  const int*   e_src  = (const int*)d_in[1];
  const int*   e_dst  = e_src + E;
  const float* emb    = (const float*)d_in[2];
  const float* W1l    = (const float*)d_in[3];
  const float* b1     = (const float*)d_in[4];
  const float* W1r    = (const float*)d_in[5];
  const float* W2l    = (const float*)d_in[6];
  const float* b2     = (const float*)d_in[7];
  const float* W2r    = (const float*)d_in[8];
  const float* Wc     = (const float*)d_in[9];
  const float* bc     = (const float*)d_in[10];
  float* out = (float*)d_out;

  // workspace layout (~42 MB)
  char* p = (char*)d_ws;
  _Float16* x0  = (_Float16*)p; p += (size_t)N * 128 * 2;   // x / reused as h2
  _Float16* agg = (_Float16*)p; p += (size_t)N * 128 * 2;
  _Float16* h1  = (_Float16*)p; p += (size_t)N * 128 * 2;
  _Float16* Wp1 = (_Float16*)p; p += 256 * 128 * 2;
  _Float16* Wp2 = (_Float16*)p; p += 256 * 128 * 2;
  _Float16* Wpc = (_Float16*)p; p += 128 * 16 * 2;
  int* deg     = (int*)p; p += (size_t)N * 4;
  int* cur     = (int*)p; p += (size_t)N * 4;               // adjacent to deg: one memset
  int* row_off = (int*)p; p += (size_t)(N + 1) * 4;
  int* csr     = (int*)p; p += (size_t)E * 4;

  hipMemsetAsync(deg, 0, (size_t)N * 8, stream);            // zeros deg + cur

  count_deg_k<<<(E + 255) / 256, 256, 0, stream>>>(e_dst, deg, E);
  scan_k<<<1, 1024, 0, stream>>>(deg, row_off, N);
  fill_k<<<(E + 255) / 256, 256, 0, stream>>>(e_src, e_dst, row_off, cur, csr, E);
  gather_k<<<(N * 16 + 255) / 256, 256, 0, stream>>>(entity, emb, x0, N);
  pack_k<<<16, 256, 0, stream>>>(W1l, W1r, Wp1, 8, 8, 128);
  pack_k<<<16, 256, 0, stream>>>(W2l, W2r, Wp2, 8, 8, 128);
  pack_k<<<1, 256, 0, stream>>>(Wc, Wc, Wpc, 4, 1, 16);

  int gblk = (N + 63) / 64;
  // layer 1: h1 = relu(mean_agg(x0) @ W1l + x0 @ W1r + b1)
  agg_k<<<(N + 3) / 4, 256, 0, stream>>>(x0, row_off, csr, agg, N);
  gemm_k<4, 4, 8, true, false><<<gblk, 256, 0, stream>>>(agg, x0, Wp1, b1, h1, N);
  // layer 2: h2 = mean_agg(h1) @ W2l + h1 @ W2r + b2   (h2 overwrites x0)
  agg_k<<<(N + 3) / 4, 256, 0, stream>>>(h1, row_off, csr, agg, N);
  gemm_k<4, 4, 8, false, false><<<gblk, 256, 0, stream>>>(agg, h1, Wp2, b2, x0, N);
  // classifier: out = h2 @ Wc + bc   (fp32 out)
  gemm_k<4, 0, 1, false, true><<<gblk, 256, 0, stream>>>(x0, x0, Wpc, bc, out, N);
}

// Round 2
// 271.266 us; speedup vs baseline: 1.2360x; 1.2360x over previous
//
#include <hip/hip_runtime.h>

typedef _Float16 half2v __attribute__((ext_vector_type(2)));
typedef _Float16 half8  __attribute__((ext_vector_type(8)));
typedef float    f32x4  __attribute__((ext_vector_type(4)));

// ---------------- CSR build ----------------
__global__ void count_deg_k(const int* __restrict__ dst, int* __restrict__ deg, int E) {
  int t = blockIdx.x * 256 + threadIdx.x;
  if (t < E) atomicAdd(&deg[dst[t]], 1);
}

// phase 1: per-256-chunk partial sums (shuffle reduce, wave=64)
__global__ void deg_part_k(const int* __restrict__ deg, int* __restrict__ part, int N) {
  int t = blockIdx.x * 256 + threadIdx.x;
  int v = (t < N) ? deg[t] : 0;
  v += __shfl_down(v, 32); v += __shfl_down(v, 16); v += __shfl_down(v, 8);
  v += __shfl_down(v, 4);  v += __shfl_down(v, 2);  v += __shfl_down(v, 1);
  __shared__ int sm[4];
  if ((threadIdx.x & 63) == 0) sm[threadIdx.x >> 6] = v;
  __syncthreads();
  if (threadIdx.x == 0) part[blockIdx.x] = sm[0] + sm[1] + sm[2] + sm[3];
}

// phase 2: scan the partials (single small block), exclusive; also total -> row_off[N]
__global__ void part_scan_k(int* __restrict__ part, int* __restrict__ row_off, int P, int N) {
  __shared__ int sm[256];
  int t = threadIdx.x;
  int v = (t < P) ? part[t] : 0;
  sm[t] = v; __syncthreads();
  for (int off = 1; off < 256; off <<= 1) {
    int a = sm[t];
    int b = (t >= off) ? sm[t - off] : 0;
    __syncthreads();
    sm[t] = a + b;
    __syncthreads();
  }
  if (t < P) part[t] = sm[t] - v;          // exclusive offset per chunk
  if (t == 255) row_off[N] = sm[255];      // grand total
}

// phase 3: block-local exclusive scan + chunk offset, coalesced writes
__global__ void row_off_k(const int* __restrict__ deg, const int* __restrict__ part,
                          int* __restrict__ row_off, int N) {
  __shared__ int sm[256];
  int t = blockIdx.x * 256 + threadIdx.x;
  int v = (t < N) ? deg[t] : 0;
  sm[threadIdx.x] = v; __syncthreads();
  for (int off = 1; off < 256; off <<= 1) {
    int a = sm[threadIdx.x];
    int b = (threadIdx.x >= off) ? sm[threadIdx.x - off] : 0;
    __syncthreads();
    sm[threadIdx.x] = a + b;
    __syncthreads();
  }
  if (t < N) row_off[t] = part[blockIdx.x] + sm[threadIdx.x] - v;
}

__global__ void fill_k(const int* __restrict__ src, const int* __restrict__ dst,
                       const int* __restrict__ row_off, int* __restrict__ cur,
                       int* __restrict__ csr, int E) {
  int t = blockIdx.x * 256 + threadIdx.x;
  if (t < E) {
    int d = dst[t];
    int p = atomicAdd(&cur[d], 1);
    csr[row_off[d] + p] = src[t];
  }
}

// ---------------- embedding gather (fp32 emb -> f16 x) ----------------
__global__ void gather_k(const int* __restrict__ ent, const float* __restrict__ emb,
                         _Float16* __restrict__ X, int N) {
  int t = blockIdx.x * 256 + threadIdx.x;
  if (t >= N * 16) return;
  int node = t >> 4, g = t & 15;
  const float4* s = (const float4*)(emb + (long)ent[node] * 128 + g * 8);
  float4 a = s[0], b = s[1];
  half8 o;
  o[0] = (_Float16)a.x; o[1] = (_Float16)a.y; o[2] = (_Float16)a.z; o[3] = (_Float16)a.w;
  o[4] = (_Float16)b.x; o[5] = (_Float16)b.y; o[6] = (_Float16)b.z; o[7] = (_Float16)b.w;
  *(half8*)(X + (long)t * 8) = o;
}

// ---------------- weight pack into MFMA B-fragment order ----------------
// B[k][n]: lane holds B[kt*32 + (lane>>4)*8 + j][nt*16 + (lane&15)], j=0..7, 16B contiguous.
// k < 128 -> Wa[k][n], else Wb[k-128][n] (stacked [Wl;Wr] for the concat-GEMM).
__global__ void pack_k(const float* __restrict__ Wa, const float* __restrict__ Wb,
                       _Float16* __restrict__ out, int KT, int NT, int ncols) {
  int t = blockIdx.x * 256 + threadIdx.x;
  if (t >= KT * NT * 64) return;
  int lane = t & 63, tile = t >> 6;
  int nt = tile % NT, kt = tile / NT;
  int n  = nt * 16 + (lane & 15);
  int kb = kt * 32 + (lane >> 4) * 8;
  half8 o;
#pragma unroll
  for (int j = 0; j < 8; ++j) {
    int k = kb + j;
    float w = (k < 128) ? Wa[k * ncols + n] : Wb[(k - 128) * ncols + n];
    o[j] = (_Float16)w;
  }
  *(half8*)(out + (long)t * 8) = o;
}

// ---------------- mean aggregation via CSR gather (wave per node) ----------------
__global__ void agg_k(const _Float16* __restrict__ X, const int* __restrict__ row_off,
                      const int* __restrict__ csr, _Float16* __restrict__ A, int N) {
  int node = blockIdx.x * 4 + (threadIdx.x >> 6);
  if (node >= N) return;
  int lane = threadIdx.x & 63;          // lane covers dims 2*lane, 2*lane+1
  int beg = row_off[node], end = row_off[node + 1];
  float ax = 0.f, ay = 0.f;
#pragma unroll 4
  for (int e = beg; e < end; ++e) {
    half2v v = *(const half2v*)(X + (long)csr[e] * 128 + lane * 2);
    ax += (float)v[0]; ay += (float)v[1];
  }
  float inv = 1.f / fmaxf((float)(end - beg), 1.f);
  half2v o; o[0] = (_Float16)(ax * inv); o[1] = (_Float16)(ay * inv);
  *(half2v*)(A + (long)node * 128 + lane * 2) = o;
}

// ---------------- fused concat-GEMM: Out = act([A1|A2] @ Bp + bias) ----------------
// Block = 4 waves, 64 rows. Wave: 16 rows x NT*16 cols, K = (KT1+KT2)*32.
// A-frag: lane holds A[row0 + (lane&15)][kt*32 + (lane>>4)*8 + j]  (one dwordx4)
// D-frag: col = lane&15, row = (lane>>4)*4 + reg                   (guide m89/m91)
template <int KT1, int KT2, int NT, bool RELU, bool OUTF32>
__global__ __launch_bounds__(256) void gemm_k(const _Float16* __restrict__ A1,
                                              const _Float16* __restrict__ A2,
                                              const _Float16* __restrict__ Bp,
                                              const float* __restrict__ bias,
                                              void* __restrict__ Outv, int M) {
  constexpr int KT = KT1 + KT2;
  constexpr int N  = NT * 16;
  int wave = threadIdx.x >> 6, lane = threadIdx.x & 63;
  int row0 = blockIdx.x * 64 + wave * 16;
  int m = lane & 15, quad = lane >> 4;
  int arow = row0 + m; if (arow > M - 1) arow = M - 1;   // clamp tail loads
  f32x4 acc[NT];
#pragma unroll
  for (int i = 0; i < NT; ++i) acc[i] = (f32x4){0.f, 0.f, 0.f, 0.f};
#pragma unroll
  for (int kt = 0; kt < KT; ++kt) {
    const _Float16* s = (kt < KT1) ? (A1 + (long)arow * (KT1 * 32) + kt * 32)
                                   : (A2 + (long)arow * (KT2 * 32) + (kt - KT1) * 32);
    half8 af = *(const half8*)(s + quad * 8);
#pragma unroll
    for (int nt = 0; nt < NT; ++nt) {
      half8 bf = *(const half8*)(Bp + ((long)(kt * NT + nt) * 64 + lane) * 8);
      acc[nt] = __builtin_amdgcn_mfma_f32_16x16x32_f16(af, bf, acc[nt], 0, 0, 0);
    }
  }
#pragma unroll
  for (int nt = 0; nt < NT; ++nt) {
    float bv = bias[nt * 16 + m];
#pragma unroll
    for (int r = 0; r < 4; ++r) {
      int orow = row0 + quad * 4 + r;
      if (orow < M) {
        float v = acc[nt][r] + bv;
        if (RELU) v = fmaxf(v, 0.f);
        long oi = (long)orow * N + nt * 16 + m;
        if (OUTF32) ((float*)Outv)[oi] = v;
        else        ((_Float16*)Outv)[oi] = (_Float16)v;
      }
    }
  }
}

extern "C" void kernel_launch(void* const* d_in, const int* in_sizes, int n_in,
                              void* d_out, int out_size, void* d_ws, size_t ws_size,
                              hipStream_t stream) {
  const int N = in_sizes[0];
  const int E = in_sizes[1] / 2;
  const int*   entity = (const int*)d_in[0];
  const int*   e_src  = (const int*)d_in[1];
  const int*   e_dst  = e_src + E;
  const float* emb    = (const float*)d_in[2];
  const float* W1l    = (const float*)d_in[3];
  const float* b1     = (const float*)d_in[4];
  const float* W1r    = (const float*)d_in[5];
  const float* W2l    = (const float*)d_in[6];
  const float* b2     = (const float*)d_in[7];
  const float* W2r    = (const float*)d_in[8];
  const float* Wc     = (const float*)d_in[9];
  const float* bc     = (const float*)d_in[10];
  float* out = (float*)d_out;

  // workspace layout (~42 MB)
  char* p = (char*)d_ws;
  _Float16* x0  = (_Float16*)p; p += (size_t)N * 128 * 2;   // x / reused as h2
  _Float16* agg = (_Float16*)p; p += (size_t)N * 128 * 2;
  _Float16* h1  = (_Float16*)p; p += (size_t)N * 128 * 2;
  _Float16* Wp1 = (_Float16*)p; p += 256 * 128 * 2;
  _Float16* Wp2 = (_Float16*)p; p += 256 * 128 * 2;
  _Float16* Wpc = (_Float16*)p; p += 128 * 16 * 2;
  int* deg     = (int*)p; p += (size_t)N * 4;
  int* cur     = (int*)p; p += (size_t)N * 4;               // adjacent to deg: one memset
  int* row_off = (int*)p; p += (size_t)(N + 1) * 4;
  int* csr     = (int*)p; p += (size_t)E * 4;
  int* part    = (int*)p; p += 1024 * 4;                    // scan partials

  const int NB = (N + 255) / 256;                           // 196 chunks

  hipMemsetAsync(deg, 0, (size_t)N * 8, stream);            // zeros deg + cur

  count_deg_k<<<(E + 255) / 256, 256, 0, stream>>>(e_dst, deg, E);
  deg_part_k<<<NB, 256, 0, stream>>>(deg, part, N);
  part_scan_k<<<1, 256, 0, stream>>>(part, row_off, NB, N);
  row_off_k<<<NB, 256, 0, stream>>>(deg, part, row_off, N);
  fill_k<<<(E + 255) / 256, 256, 0, stream>>>(e_src, e_dst, row_off, cur, csr, E);
  gather_k<<<(N * 16 + 255) / 256, 256, 0, stream>>>(entity, emb, x0, N);
  pack_k<<<16, 256, 0, stream>>>(W1l, W1r, Wp1, 8, 8, 128);
  pack_k<<<16, 256, 0, stream>>>(W2l, W2r, Wp2, 8, 8, 128);
  pack_k<<<1, 256, 0, stream>>>(Wc, Wc, Wpc, 4, 1, 16);

  int gblk = (N + 63) / 64;
  // layer 1: h1 = relu(mean_agg(x0) @ W1l + x0 @ W1r + b1)
  agg_k<<<(N + 3) / 4, 256, 0, stream>>>(x0, row_off, csr, agg, N);
  gemm_k<4, 4, 8, true, false><<<gblk, 256, 0, stream>>>(agg, x0, Wp1, b1, h1, N);
  // layer 2: h2 = mean_agg(h1) @ W2l + h1 @ W2r + b2   (h2 overwrites x0)
  agg_k<<<(N + 3) / 4, 256, 0, stream>>>(h1, row_off, csr, agg, N);
  gemm_k<4, 4, 8, false, false><<<gblk, 256, 0, stream>>>(agg, h1, Wp2, b2, x0, N);
  // classifier: out = h2 @ Wc + bc   (fp32 out)
  gemm_k<4, 0, 1, false, true><<<gblk, 256, 0, stream>>>(x0, x0, Wpc, bc, out, N);
}

// Round 3
// 244.912 us; speedup vs baseline: 1.3690x; 1.1076x over previous
//
#include <hip/hip_runtime.h>

typedef _Float16 half2v __attribute__((ext_vector_type(2)));
typedef _Float16 half8  __attribute__((ext_vector_type(8)));
typedef float    f32x4  __attribute__((ext_vector_type(4)));

// ---------------- CSR build ----------------
__global__ void count_deg_k(const int* __restrict__ dst, int* __restrict__ deg, int E) {
  int t = blockIdx.x * 256 + threadIdx.x;
  if (t < E) atomicAdd(&deg[dst[t]], 1);
}

// phase 1: per-256-chunk partial sums (shuffle reduce, wave=64)
__global__ void deg_part_k(const int* __restrict__ deg, int* __restrict__ part, int N) {
  int t = blockIdx.x * 256 + threadIdx.x;
  int v = (t < N) ? deg[t] : 0;
  v += __shfl_down(v, 32); v += __shfl_down(v, 16); v += __shfl_down(v, 8);
  v += __shfl_down(v, 4);  v += __shfl_down(v, 2);  v += __shfl_down(v, 1);
  __shared__ int sm[4];
  if ((threadIdx.x & 63) == 0) sm[threadIdx.x >> 6] = v;
  __syncthreads();
  if (threadIdx.x == 0) part[blockIdx.x] = sm[0] + sm[1] + sm[2] + sm[3];
}

// phase 2: scan the partials (single small block), exclusive; also total -> row_off[N]
__global__ void part_scan_k(int* __restrict__ part, int* __restrict__ row_off, int P, int N) {
  __shared__ int sm[256];
  int t = threadIdx.x;
  int v = (t < P) ? part[t] : 0;
  sm[t] = v; __syncthreads();
  for (int off = 1; off < 256; off <<= 1) {
    int a = sm[t];
    int b = (t >= off) ? sm[t - off] : 0;
    __syncthreads();
    sm[t] = a + b;
    __syncthreads();
  }
  if (t < P) part[t] = sm[t] - v;          // exclusive offset per chunk
  if (t == 255) row_off[N] = sm[255];      // grand total
}

// phase 3: block-local exclusive scan + chunk offset, coalesced writes
__global__ void row_off_k(const int* __restrict__ deg, const int* __restrict__ part,
                          int* __restrict__ row_off, int N) {
  __shared__ int sm[256];
  int t = blockIdx.x * 256 + threadIdx.x;
  int v = (t < N) ? deg[t] : 0;
  sm[threadIdx.x] = v; __syncthreads();
  for (int off = 1; off < 256; off <<= 1) {
    int a = sm[threadIdx.x];
    int b = (threadIdx.x >= off) ? sm[threadIdx.x - off] : 0;
    __syncthreads();
    sm[threadIdx.x] = a + b;
    __syncthreads();
  }
  if (t < N) row_off[t] = part[blockIdx.x] + sm[threadIdx.x] - v;
}

__global__ void fill_k(const int* __restrict__ src, const int* __restrict__ dst,
                       const int* __restrict__ row_off, int* __restrict__ cur,
                       int* __restrict__ csr, int E) {
  int t = blockIdx.x * 256 + threadIdx.x;
  if (t < E) {
    int d = dst[t];
    int p = atomicAdd(&cur[d], 1);
    csr[row_off[d] + p] = src[t];
  }
}

// ---------------- fused prep: embedding gather + all 3 weight packs ----------------
// blocks [0, GB): gather emb[entity] -> f16 X
// blocks [GB, GB+16): pack W1 (KT=8,NT=8)   blocks [GB+16, GB+32): pack W2
// block  GB+32: pack Wc (KT=4,NT=1)
// B-frag order: lane holds B[kt*32+(lane>>4)*8+j][nt*16+(lane&15)], j=0..7, 16B contiguous.
__device__ __forceinline__ void pack_dev(const float* Wa, const float* Wb,
                                         _Float16* out, int NT, int ncols, int t) {
  int lane = t & 63, tile = t >> 6;
  int nt = tile % NT, kt = tile / NT;
  int n  = nt * 16 + (lane & 15);
  int kb = kt * 32 + (lane >> 4) * 8;
  half8 o;
#pragma unroll
  for (int j = 0; j < 8; ++j) {
    int k = kb + j;
    float w = (k < 128) ? Wa[k * ncols + n] : Wb[(k - 128) * ncols + n];
    o[j] = (_Float16)w;
  }
  *(half8*)(out + (long)t * 8) = o;
}

__global__ void prep_k(const int* __restrict__ ent, const float* __restrict__ emb,
                       _Float16* __restrict__ X,
                       const float* __restrict__ W1l, const float* __restrict__ W1r, _Float16* __restrict__ Wp1,
                       const float* __restrict__ W2l, const float* __restrict__ W2r, _Float16* __restrict__ Wp2,
                       const float* __restrict__ Wc, _Float16* __restrict__ Wpc,
                       int N, int GB) {
  int b = blockIdx.x;
  if (b < GB) {
    int t = b * 256 + threadIdx.x;
    if (t >= N * 16) return;
    int node = t >> 4, g = t & 15;
    const float4* s = (const float4*)(emb + (long)ent[node] * 128 + g * 8);
    float4 a = s[0], c = s[1];
    half8 o;
    o[0] = (_Float16)a.x; o[1] = (_Float16)a.y; o[2] = (_Float16)a.z; o[3] = (_Float16)a.w;
    o[4] = (_Float16)c.x; o[5] = (_Float16)c.y; o[6] = (_Float16)c.z; o[7] = (_Float16)c.w;
    *(half8*)(X + (long)t * 8) = o;
  } else if (b < GB + 16) {
    pack_dev(W1l, W1r, Wp1, 8, 128, (b - GB) * 256 + threadIdx.x);
  } else if (b < GB + 32) {
    pack_dev(W2l, W2r, Wp2, 8, 128, (b - GB - 16) * 256 + threadIdx.x);
  } else {
    pack_dev(Wc, Wc, Wpc, 1, 16, threadIdx.x);   // KT=4,NT=1 -> 256 threads
  }
}

// ---------------- mean aggregation: 16-lane group per node, half8 loads ----------------
// lane l of the group covers dims l*8 .. l*8+7 (one dwordx4 per edge).
// 4 nodes per wave -> 4 independent edge streams in flight + unroll-4 MLP.
__global__ void agg_k(const _Float16* __restrict__ X, const int* __restrict__ row_off,
                      const int* __restrict__ csr, _Float16* __restrict__ A, int N) {
  int grp = (blockIdx.x * 256 + threadIdx.x) >> 4;   // node id
  if (grp >= N) return;
  int lane = threadIdx.x & 15;
  int beg = row_off[grp], end = row_off[grp + 1];
  float a0 = 0.f, a1 = 0.f, a2 = 0.f, a3 = 0.f, a4 = 0.f, a5 = 0.f, a6 = 0.f, a7 = 0.f;
#pragma unroll 4
  for (int e = beg; e < end; ++e) {
    half8 v = *(const half8*)(X + (long)csr[e] * 128 + lane * 8);
    a0 += (float)v[0]; a1 += (float)v[1]; a2 += (float)v[2]; a3 += (float)v[3];
    a4 += (float)v[4]; a5 += (float)v[5]; a6 += (float)v[6]; a7 += (float)v[7];
  }
  float inv = 1.f / fmaxf((float)(end - beg), 1.f);
  half8 o;
  o[0] = (_Float16)(a0 * inv); o[1] = (_Float16)(a1 * inv);
  o[2] = (_Float16)(a2 * inv); o[3] = (_Float16)(a3 * inv);
  o[4] = (_Float16)(a4 * inv); o[5] = (_Float16)(a5 * inv);
  o[6] = (_Float16)(a6 * inv); o[7] = (_Float16)(a7 * inv);
  *(half8*)(A + (long)grp * 128 + lane * 8) = o;
}

// ---------------- fused concat-GEMM: Out = act([A1|A2] @ Bp + bias) ----------------
// Block = 4 waves, 64 rows. Wave: 16 rows x NT*16 cols, K = (KT1+KT2)*32.
// A-frag: lane holds A[row0 + (lane&15)][kt*32 + (lane>>4)*8 + j]  (one dwordx4)
// D-frag: col = lane&15, row = (lane>>4)*4 + reg                   (guide m89/m91)
template <int KT1, int KT2, int NT, bool RELU, bool OUTF32>
__global__ __launch_bounds__(256) void gemm_k(const _Float16* __restrict__ A1,
                                              const _Float16* __restrict__ A2,
                                              const _Float16* __restrict__ Bp,
                                              const float* __restrict__ bias,
                                              void* __restrict__ Outv, int M) {
  constexpr int KT = KT1 + KT2;
  constexpr int N  = NT * 16;
  int wave = threadIdx.x >> 6, lane = threadIdx.x & 63;
  int row0 = blockIdx.x * 64 + wave * 16;
  int m = lane & 15, quad = lane >> 4;
  int arow = row0 + m; if (arow > M - 1) arow = M - 1;   // clamp tail loads
  f32x4 acc[NT];
#pragma unroll
  for (int i = 0; i < NT; ++i) acc[i] = (f32x4){0.f, 0.f, 0.f, 0.f};
#pragma unroll
  for (int kt = 0; kt < KT; ++kt) {
    const _Float16* s = (kt < KT1) ? (A1 + (long)arow * (KT1 * 32) + kt * 32)
                                   : (A2 + (long)arow * (KT2 * 32) + (kt - KT1) * 32);
    half8 af = *(const half8*)(s + quad * 8);
#pragma unroll
    for (int nt = 0; nt < NT; ++nt) {
      half8 bf = *(const half8*)(Bp + ((long)(kt * NT + nt) * 64 + lane) * 8);
      acc[nt] = __builtin_amdgcn_mfma_f32_16x16x32_f16(af, bf, acc[nt], 0, 0, 0);
    }
  }
#pragma unroll
  for (int nt = 0; nt < NT; ++nt) {
    float bv = bias[nt * 16 + m];
#pragma unroll
    for (int r = 0; r < 4; ++r) {
      int orow = row0 + quad * 4 + r;
      if (orow < M) {
        float v = acc[nt][r] + bv;
        if (RELU) v = fmaxf(v, 0.f);
        long oi = (long)orow * N + nt * 16 + m;
        if (OUTF32) ((float*)Outv)[oi] = v;
        else        ((_Float16*)Outv)[oi] = (_Float16)v;
      }
    }
  }
}

extern "C" void kernel_launch(void* const* d_in, const int* in_sizes, int n_in,
                              void* d_out, int out_size, void* d_ws, size_t ws_size,
                              hipStream_t stream) {
  const int N = in_sizes[0];
  const int E = in_sizes[1] / 2;
  const int*   entity = (const int*)d_in[0];
  const int*   e_src  = (const int*)d_in[1];
  const int*   e_dst  = e_src + E;
  const float* emb    = (const float*)d_in[2];
  const float* W1l    = (const float*)d_in[3];
  const float* b1     = (const float*)d_in[4];
  const float* W1r    = (const float*)d_in[5];
  const float* W2l    = (const float*)d_in[6];
  const float* b2     = (const float*)d_in[7];
  const float* W2r    = (const float*)d_in[8];
  const float* Wc     = (const float*)d_in[9];
  const float* bc     = (const float*)d_in[10];
  float* out = (float*)d_out;

  // workspace layout (~42 MB)
  char* p = (char*)d_ws;
  _Float16* x0  = (_Float16*)p; p += (size_t)N * 128 * 2;   // x / reused as h2
  _Float16* agg = (_Float16*)p; p += (size_t)N * 128 * 2;
  _Float16* h1  = (_Float16*)p; p += (size_t)N * 128 * 2;
  _Float16* Wp1 = (_Float16*)p; p += 256 * 128 * 2;
  _Float16* Wp2 = (_Float16*)p; p += 256 * 128 * 2;
  _Float16* Wpc = (_Float16*)p; p += 128 * 16 * 2;
  int* deg     = (int*)p; p += (size_t)N * 4;
  int* cur     = (int*)p; p += (size_t)N * 4;               // adjacent to deg: one memset
  int* row_off = (int*)p; p += (size_t)(N + 1) * 4;
  int* csr     = (int*)p; p += (size_t)E * 4;
  int* part    = (int*)p; p += 1024 * 4;                    // scan partials

  const int NB = (N + 255) / 256;                           // 196 chunks
  const int GB = (N * 16 + 255) / 256;                      // gather blocks

  hipMemsetAsync(deg, 0, (size_t)N * 8, stream);            // zeros deg + cur

  count_deg_k<<<(E + 255) / 256, 256, 0, stream>>>(e_dst, deg, E);
  deg_part_k<<<NB, 256, 0, stream>>>(deg, part, N);
  part_scan_k<<<1, 256, 0, stream>>>(part, row_off, NB, N);
  row_off_k<<<NB, 256, 0, stream>>>(deg, part, row_off, N);
  fill_k<<<(E + 255) / 256, 256, 0, stream>>>(e_src, e_dst, row_off, cur, csr, E);
  prep_k<<<GB + 33, 256, 0, stream>>>(entity, emb, x0, W1l, W1r, Wp1,
                                      W2l, W2r, Wp2, Wc, Wpc, N, GB);

  int gblk = (N + 63) / 64;
  int ablk = (N * 16 + 255) / 256;
  // layer 1: h1 = relu(mean_agg(x0) @ W1l + x0 @ W1r + b1)
  agg_k<<<ablk, 256, 0, stream>>>(x0, row_off, csr, agg, N);
  gemm_k<4, 4, 8, true, false><<<gblk, 256, 0, stream>>>(agg, x0, Wp1, b1, h1, N);
  // layer 2: h2 = mean_agg(h1) @ W2l + h1 @ W2r + b2   (h2 overwrites x0)
  agg_k<<<ablk, 256, 0, stream>>>(h1, row_off, csr, agg, N);
  gemm_k<4, 4, 8, false, false><<<gblk, 256, 0, stream>>>(agg, h1, Wp2, b2, x0, N);
  // classifier: out = h2 @ Wc + bc   (fp32 out)
  gemm_k<4, 0, 1, false, true><<<gblk, 256, 0, stream>>>(x0, x0, Wpc, bc, out, N);
}

// Round 4
// 235.596 us; speedup vs baseline: 1.4232x; 1.0395x over previous
//
#include <hip/hip_runtime.h>

typedef _Float16 half8  __attribute__((ext_vector_type(8)));
typedef float    f32x4  __attribute__((ext_vector_type(4)));

// ---------------- CSR build ----------------
__global__ void count_deg_k(const int* __restrict__ dst, int* __restrict__ deg, int E) {
  int t = blockIdx.x * 256 + threadIdx.x;
  if (t < E) atomicAdd(&deg[dst[t]], 1);
}

// per-256-chunk partial sums (shuffle reduce, wave=64)
__global__ void deg_part_k(const int* __restrict__ deg, int* __restrict__ part, int N) {
  int t = blockIdx.x * 256 + threadIdx.x;
  int v = (t < N) ? deg[t] : 0;
  v += __shfl_down(v, 32); v += __shfl_down(v, 16); v += __shfl_down(v, 8);
  v += __shfl_down(v, 4);  v += __shfl_down(v, 2);  v += __shfl_down(v, 1);
  __shared__ int sm[4];
  if ((threadIdx.x & 63) == 0) sm[threadIdx.x >> 6] = v;
  __syncthreads();
  if (threadIdx.x == 0) part[blockIdx.x] = sm[0] + sm[1] + sm[2] + sm[3];
}

// row_off: every block scans the NB partials itself (LDS), then scans its own chunk.
__global__ void row_off_k(const int* __restrict__ deg, const int* __restrict__ part,
                          int* __restrict__ row_off, int N, int NB) {
  __shared__ int ps[256];
  __shared__ int sm[256];
  int tl = threadIdx.x;
  int pv = (tl < NB) ? part[tl] : 0;
  ps[tl] = pv; __syncthreads();
  for (int off = 1; off < 256; off <<= 1) {
    int a = ps[tl]; int b = (tl >= off) ? ps[tl - off] : 0;
    __syncthreads(); ps[tl] = a + b; __syncthreads();
  }
  int chunk_off = (blockIdx.x > 0) ? ps[blockIdx.x - 1] : 0;
  if (blockIdx.x == 0 && tl == 255) row_off[N] = ps[255];   // grand total
  int t = blockIdx.x * 256 + tl;
  int v = (t < N) ? deg[t] : 0;
  sm[tl] = v; __syncthreads();
  for (int off = 1; off < 256; off <<= 1) {
    int a = sm[tl]; int b = (tl >= off) ? sm[tl - off] : 0;
    __syncthreads(); sm[tl] = a + b; __syncthreads();
  }
  if (t < N) row_off[t] = chunk_off + sm[tl] - v;
}

// ---------------- fused build: CSR fill + embedding gather + weight packs ----------------
// B-frag order: lane holds B[kt*32+(lane>>4)*8+j][nt*16+(lane&15)], j=0..7, 16B contiguous.
__device__ __forceinline__ void pack_dev(const float* Wa, const float* Wb,
                                         _Float16* out, int NT, int ncols, int t) {
  int lane = t & 63, tile = t >> 6;
  int nt = tile % NT, kt = tile / NT;
  int n  = nt * 16 + (lane & 15);
  int kb = kt * 32 + (lane >> 4) * 8;
  half8 o;
#pragma unroll
  for (int j = 0; j < 8; ++j) {
    int k = kb + j;
    float w = (k < 128) ? Wa[k * ncols + n] : Wb[(k - 128) * ncols + n];
    o[j] = (_Float16)w;
  }
  *(half8*)(out + (long)t * 8) = o;
}

__global__ void build_k(const int* __restrict__ src, const int* __restrict__ dst,
                        const int* __restrict__ row_off, int* __restrict__ cur,
                        int* __restrict__ csr,
                        const int* __restrict__ ent, const float* __restrict__ emb,
                        _Float16* __restrict__ X,
                        const float* __restrict__ W1l, const float* __restrict__ W1r, _Float16* __restrict__ Wp1,
                        const float* __restrict__ W2l, const float* __restrict__ W2r, _Float16* __restrict__ Wp2,
                        const float* __restrict__ Wc, _Float16* __restrict__ Wpc,
                        int N, int E, int FB, int GB) {
  int b = blockIdx.x;
  if (b < FB) {                                    // CSR fill
    int t = b * 256 + threadIdx.x;
    if (t < E) {
      int d = dst[t];
      int p = atomicAdd(&cur[d], 1);
      csr[row_off[d] + p] = src[t];
    }
  } else if (b < FB + GB) {                        // embedding gather -> f16
    int t = (b - FB) * 256 + threadIdx.x;
    if (t >= N * 16) return;
    int node = t >> 4, g = t & 15;
    const float4* s = (const float4*)(emb + (long)ent[node] * 128 + g * 8);
    float4 a = s[0], c = s[1];
    half8 o;
    o[0] = (_Float16)a.x; o[1] = (_Float16)a.y; o[2] = (_Float16)a.z; o[3] = (_Float16)a.w;
    o[4] = (_Float16)c.x; o[5] = (_Float16)c.y; o[6] = (_Float16)c.z; o[7] = (_Float16)c.w;
    *(half8*)(X + (long)t * 8) = o;
  } else if (b < FB + GB + 16) {
    pack_dev(W1l, W1r, Wp1, 8, 128, (b - FB - GB) * 256 + threadIdx.x);
  } else if (b < FB + GB + 32) {
    pack_dev(W2l, W2r, Wp2, 8, 128, (b - FB - GB - 16) * 256 + threadIdx.x);
  } else {
    pack_dev(Wc, Wc, Wpc, 1, 16, threadIdx.x);     // KT=4, NT=1
  }
}

// ---------------- mean aggregation: 16-lane group per node, half8 loads ----------------
__global__ void agg_k(const _Float16* __restrict__ X, const int* __restrict__ row_off,
                      const int* __restrict__ csr, _Float16* __restrict__ A, int N) {
  int grp = (blockIdx.x * 256 + threadIdx.x) >> 4;   // node id
  if (grp >= N) return;
  int lane = threadIdx.x & 15;
  int beg = row_off[grp], end = row_off[grp + 1];
  float a0 = 0.f, a1 = 0.f, a2 = 0.f, a3 = 0.f, a4 = 0.f, a5 = 0.f, a6 = 0.f, a7 = 0.f;
#pragma unroll 4
  for (int e = beg; e < end; ++e) {
    half8 v = *(const half8*)(X + (long)csr[e] * 128 + lane * 8);
    a0 += (float)v[0]; a1 += (float)v[1]; a2 += (float)v[2]; a3 += (float)v[3];
    a4 += (float)v[4]; a5 += (float)v[5]; a6 += (float)v[6]; a7 += (float)v[7];
  }
  float inv = 1.f / fmaxf((float)(end - beg), 1.f);
  half8 o;
  o[0] = (_Float16)(a0 * inv); o[1] = (_Float16)(a1 * inv);
  o[2] = (_Float16)(a2 * inv); o[3] = (_Float16)(a3 * inv);
  o[4] = (_Float16)(a4 * inv); o[5] = (_Float16)(a5 * inv);
  o[6] = (_Float16)(a6 * inv); o[7] = (_Float16)(a7 * inv);
  *(half8*)(A + (long)grp * 128 + lane * 8) = o;
}

// ---------------- layer-1 concat-GEMM: h1 = relu([agg|x] @ Wp1 + b1) ----------------
// Block = 4 waves, 64 rows. Wave: 16 rows x 128 cols, K = 256.
// A-frag: lane holds A[row0+(lane&15)][kt*32+(lane>>4)*8+j]; D: col=lane&15, row=(lane>>4)*4+reg.
__global__ __launch_bounds__(256) void gemm1_k(const _Float16* __restrict__ A1,
                                               const _Float16* __restrict__ A2,
                                               const _Float16* __restrict__ Bp,
                                               const float* __restrict__ bias,
                                               _Float16* __restrict__ Out, int M) {
  int wave = threadIdx.x >> 6, lane = threadIdx.x & 63;
  int row0 = blockIdx.x * 64 + wave * 16;
  int m = lane & 15, quad = lane >> 4;
  int arow = row0 + m; if (arow > M - 1) arow = M - 1;
  f32x4 acc[8];
#pragma unroll
  for (int i = 0; i < 8; ++i) acc[i] = (f32x4){0.f, 0.f, 0.f, 0.f};
#pragma unroll
  for (int kt = 0; kt < 8; ++kt) {
    const _Float16* s = (kt < 4) ? (A1 + (long)arow * 128 + kt * 32)
                                 : (A2 + (long)arow * 128 + (kt - 4) * 32);
    half8 af = *(const half8*)(s + quad * 8);
#pragma unroll
    for (int nt = 0; nt < 8; ++nt) {
      half8 bf = *(const half8*)(Bp + ((long)(kt * 8 + nt) * 64 + lane) * 8);
      acc[nt] = __builtin_amdgcn_mfma_f32_16x16x32_f16(af, bf, acc[nt], 0, 0, 0);
    }
  }
#pragma unroll
  for (int nt = 0; nt < 8; ++nt) {
    float bv = bias[nt * 16 + m];
#pragma unroll
    for (int r = 0; r < 4; ++r) {
      int orow = row0 + quad * 4 + r;
      if (orow < M)
        Out[(long)orow * 128 + nt * 16 + m] = (_Float16)fmaxf(acc[nt][r] + bv, 0.f);
    }
  }
}

// ---------------- layer-2 GEMM fused with classifier ----------------
// h2 tile (16x128/wave) stays on-chip: acc -> +b2 -> LDS (stride 136) -> A-frags -> @Wpc -> out.
__global__ __launch_bounds__(256) void gemm2cls_k(const _Float16* __restrict__ A1,
                                                  const _Float16* __restrict__ A2,
                                                  const _Float16* __restrict__ Bp,
                                                  const float* __restrict__ bias,
                                                  const _Float16* __restrict__ Bpc,
                                                  const float* __restrict__ bc,
                                                  float* __restrict__ out, int M) {
  __shared__ _Float16 hbuf[4][16 * 136];   // per-wave 16x128, +8 f16 row pad (2-way banks: free)
  int wave = threadIdx.x >> 6, lane = threadIdx.x & 63;
  int row0 = blockIdx.x * 64 + wave * 16;
  int m = lane & 15, quad = lane >> 4;
  int arow = row0 + m; if (arow > M - 1) arow = M - 1;
  f32x4 acc[8];
#pragma unroll
  for (int i = 0; i < 8; ++i) acc[i] = (f32x4){0.f, 0.f, 0.f, 0.f};
#pragma unroll
  for (int kt = 0; kt < 8; ++kt) {
    const _Float16* s = (kt < 4) ? (A1 + (long)arow * 128 + kt * 32)
                                 : (A2 + (long)arow * 128 + (kt - 4) * 32);
    half8 af = *(const half8*)(s + quad * 8);
#pragma unroll
    for (int nt = 0; nt < 8; ++nt) {
      half8 bf = *(const half8*)(Bp + ((long)(kt * 8 + nt) * 64 + lane) * 8);
      acc[nt] = __builtin_amdgcn_mfma_f32_16x16x32_f16(af, bf, acc[nt], 0, 0, 0);
    }
  }
  _Float16* hb = hbuf[wave];
#pragma unroll
  for (int nt = 0; nt < 8; ++nt) {
    float bv = bias[nt * 16 + m];
#pragma unroll
    for (int r = 0; r < 4; ++r)
      hb[(quad * 4 + r) * 136 + nt * 16 + m] = (_Float16)(acc[nt][r] + bv);
  }
  __syncthreads();                        // order LDS writes before cross-lane reads
  f32x4 c2 = (f32x4){0.f, 0.f, 0.f, 0.f};
#pragma unroll
  for (int kt = 0; kt < 4; ++kt) {
    half8 af = *(const half8*)(hb + m * 136 + kt * 32 + quad * 8);
    half8 bf = *(const half8*)(Bpc + ((long)(kt * 64 + lane)) * 8);
    c2 = __builtin_amdgcn_mfma_f32_16x16x32_f16(af, bf, c2, 0, 0, 0);
  }
#pragma unroll
  for (int r = 0; r < 4; ++r) {
    int orow = row0 + quad * 4 + r;
    if (orow < M) out[(long)orow * 16 + m] = c2[r] + bc[m];
  }
}

extern "C" void kernel_launch(void* const* d_in, const int* in_sizes, int n_in,
                              void* d_out, int out_size, void* d_ws, size_t ws_size,
                              hipStream_t stream) {
  const int N = in_sizes[0];
  const int E = in_sizes[1] / 2;
  const int*   entity = (const int*)d_in[0];
  const int*   e_src  = (const int*)d_in[1];
  const int*   e_dst  = e_src + E;
  const float* emb    = (const float*)d_in[2];
  const float* W1l    = (const float*)d_in[3];
  const float* b1     = (const float*)d_in[4];
  const float* W1r    = (const float*)d_in[5];
  const float* W2l    = (const float*)d_in[6];
  const float* b2     = (const float*)d_in[7];
  const float* W2r    = (const float*)d_in[8];
  const float* Wc     = (const float*)d_in[9];
  const float* bc     = (const float*)d_in[10];
  float* out = (float*)d_out;

  // workspace layout
  char* p = (char*)d_ws;
  _Float16* x0  = (_Float16*)p; p += (size_t)N * 128 * 2;
  _Float16* agg = (_Float16*)p; p += (size_t)N * 128 * 2;
  _Float16* h1  = (_Float16*)p; p += (size_t)N * 128 * 2;
  _Float16* Wp1 = (_Float16*)p; p += 256 * 128 * 2;
  _Float16* Wp2 = (_Float16*)p; p += 256 * 128 * 2;
  _Float16* Wpc = (_Float16*)p; p += 128 * 16 * 2;
  int* deg     = (int*)p; p += (size_t)N * 4;
  int* cur     = (int*)p; p += (size_t)N * 4;               // adjacent to deg: one memset
  int* row_off = (int*)p; p += (size_t)(N + 1) * 4;
  int* csr     = (int*)p; p += (size_t)E * 4;
  int* part    = (int*)p; p += 1024 * 4;

  const int NB = (N + 255) / 256;          // 196
  const int FB = (E + 255) / 256;          // 2344
  const int GB = (N * 16 + 255) / 256;     // 3125

  hipMemsetAsync(deg, 0, (size_t)N * 8, stream);            // zeros deg + cur

  count_deg_k<<<FB, 256, 0, stream>>>(e_dst, deg, E);
  deg_part_k<<<NB, 256, 0, stream>>>(deg, part, N);
  row_off_k<<<NB, 256, 0, stream>>>(deg, part, row_off, N, NB);
  build_k<<<FB + GB + 33, 256, 0, stream>>>(e_src, e_dst, row_off, cur, csr,
                                            entity, emb, x0,
                                            W1l, W1r, Wp1, W2l, W2r, Wp2, Wc, Wpc,
                                            N, E, FB, GB);

  int gblk = (N + 63) / 64;
  int ablk = (N * 16 + 255) / 256;
  // layer 1: h1 = relu(mean_agg(x0) @ W1l + x0 @ W1r + b1)
  agg_k<<<ablk, 256, 0, stream>>>(x0, row_off, csr, agg, N);
  gemm1_k<<<gblk, 256, 0, stream>>>(agg, x0, Wp1, b1, h1, N);
  // layer 2 + classifier fused: out = (mean_agg(h1) @ W2l + h1 @ W2r + b2) @ Wc + bc
  agg_k<<<ablk, 256, 0, stream>>>(h1, row_off, csr, agg, N);
  gemm2cls_k<<<gblk, 256, 0, stream>>>(agg, h1, Wp2, b2, Wpc, bc, out, N);
}

// Round 5
// 229.067 us; speedup vs baseline: 1.4637x; 1.0285x over previous
//
#include <hip/hip_runtime.h>

typedef _Float16 half8  __attribute__((ext_vector_type(8)));
typedef float    f32x4  __attribute__((ext_vector_type(4)));

// ---------------- CSR build ----------------
__global__ void count_deg_k(const int* __restrict__ dst, int* __restrict__ deg, int E) {
  int t = blockIdx.x * 256 + threadIdx.x;
  if (t < E) atomicAdd(&deg[dst[t]], 1);
}

// per-256-chunk partial sums (shuffle reduce, wave=64)
__global__ void deg_part_k(const int* __restrict__ deg, int* __restrict__ part, int N) {
  int t = blockIdx.x * 256 + threadIdx.x;
  int v = (t < N) ? deg[t] : 0;
  v += __shfl_down(v, 32); v += __shfl_down(v, 16); v += __shfl_down(v, 8);
  v += __shfl_down(v, 4);  v += __shfl_down(v, 2);  v += __shfl_down(v, 1);
  __shared__ int sm[4];
  if ((threadIdx.x & 63) == 0) sm[threadIdx.x >> 6] = v;
  __syncthreads();
  if (threadIdx.x == 0) part[blockIdx.x] = sm[0] + sm[1] + sm[2] + sm[3];
}

// row_off: every block scans the NB partials itself (LDS), then scans its own chunk.
__global__ void row_off_k(const int* __restrict__ deg, const int* __restrict__ part,
                          int* __restrict__ row_off, int N, int NB) {
  __shared__ int ps[256];
  __shared__ int sm[256];
  int tl = threadIdx.x;
  int pv = (tl < NB) ? part[tl] : 0;
  ps[tl] = pv; __syncthreads();
  for (int off = 1; off < 256; off <<= 1) {
    int a = ps[tl]; int b = (tl >= off) ? ps[tl - off] : 0;
    __syncthreads(); ps[tl] = a + b; __syncthreads();
  }
  int chunk_off = (blockIdx.x > 0) ? ps[blockIdx.x - 1] : 0;
  if (blockIdx.x == 0 && tl == 255) row_off[N] = ps[255];   // grand total
  int t = blockIdx.x * 256 + tl;
  int v = (t < N) ? deg[t] : 0;
  sm[tl] = v; __syncthreads();
  for (int off = 1; off < 256; off <<= 1) {
    int a = sm[tl]; int b = (tl >= off) ? sm[tl - off] : 0;
    __syncthreads(); sm[tl] = a + b; __syncthreads();
  }
  if (t < N) row_off[t] = chunk_off + sm[tl] - v;
}

// ---------------- fused build: CSR fill + embedding gather + weight packs ----------------
// B-frag order: lane holds B[kt*32+(lane>>4)*8+j][nt*16+(lane&15)], j=0..7, 16B contiguous.
__device__ __forceinline__ void pack_dev(const float* Wa, const float* Wb,
                                         _Float16* out, int NT, int ncols, int t) {
  int lane = t & 63, tile = t >> 6;
  int nt = tile % NT, kt = tile / NT;
  int n  = nt * 16 + (lane & 15);
  int kb = kt * 32 + (lane >> 4) * 8;
  half8 o;
#pragma unroll
  for (int j = 0; j < 8; ++j) {
    int k = kb + j;
    float w = (k < 128) ? Wa[k * ncols + n] : Wb[(k - 128) * ncols + n];
    o[j] = (_Float16)w;
  }
  *(half8*)(out + (long)t * 8) = o;
}

__global__ void build_k(const int* __restrict__ src, const int* __restrict__ dst,
                        const int* __restrict__ row_off, int* __restrict__ cur,
                        int* __restrict__ csr,
                        const int* __restrict__ ent, const float* __restrict__ emb,
                        _Float16* __restrict__ X,
                        const float* __restrict__ W1l, const float* __restrict__ W1r, _Float16* __restrict__ Wp1,
                        const float* __restrict__ W2l, const float* __restrict__ W2r, _Float16* __restrict__ Wp2,
                        const float* __restrict__ Wc, _Float16* __restrict__ Wpc,
                        int N, int E, int FB, int GB) {
  int b = blockIdx.x;
  if (b < FB) {                                    // CSR fill
    int t = b * 256 + threadIdx.x;
    if (t < E) {
      int d = dst[t];
      int p = atomicAdd(&cur[d], 1);
      csr[row_off[d] + p] = src[t];
    }
  } else if (b < FB + GB) {                        // embedding gather -> f16
    int t = (b - FB) * 256 + threadIdx.x;
    if (t >= N * 16) return;
    int node = t >> 4, g = t & 15;
    const float4* s = (const float4*)(emb + (long)ent[node] * 128 + g * 8);
    float4 a = s[0], c = s[1];
    half8 o;
    o[0] = (_Float16)a.x; o[1] = (_Float16)a.y; o[2] = (_Float16)a.z; o[3] = (_Float16)a.w;
    o[4] = (_Float16)c.x; o[5] = (_Float16)c.y; o[6] = (_Float16)c.z; o[7] = (_Float16)c.w;
    *(half8*)(X + (long)t * 8) = o;
  } else if (b < FB + GB + 16) {
    pack_dev(W1l, W1r, Wp1, 8, 128, (b - FB - GB) * 256 + threadIdx.x);
  } else if (b < FB + GB + 32) {
    pack_dev(W2l, W2r, Wp2, 8, 128, (b - FB - GB - 16) * 256 + threadIdx.x);
  } else {
    pack_dev(Wc, Wc, Wpc, 1, 16, threadIdx.x);     // KT=4, NT=1
  }
}

// ---------------- wave-private gather+mean into LDS tile (16 rows x 128, stride 136) ----
// 16-lane group per node, 4 nodes per pass, 4 passes -> 16 rows. half8 (16B) loads.
__device__ __forceinline__ void agg_to_lds(const _Float16* __restrict__ X,
                                           const int* __restrict__ row_off,
                                           const int* __restrict__ csr,
                                           _Float16* ab, int row0, int M, int lane) {
  int g = lane >> 4, j = lane & 15;
#pragma unroll
  for (int batch = 0; batch < 4; ++batch) {
    int node = row0 + batch * 4 + g;
    int nc = (node < M) ? node : M - 1;
    int beg = row_off[nc], end = row_off[nc + 1];
    float a0 = 0.f, a1 = 0.f, a2 = 0.f, a3 = 0.f, a4 = 0.f, a5 = 0.f, a6 = 0.f, a7 = 0.f;
#pragma unroll 4
    for (int e = beg; e < end; ++e) {
      half8 v = *(const half8*)(X + (long)csr[e] * 128 + j * 8);
      a0 += (float)v[0]; a1 += (float)v[1]; a2 += (float)v[2]; a3 += (float)v[3];
      a4 += (float)v[4]; a5 += (float)v[5]; a6 += (float)v[6]; a7 += (float)v[7];
    }
    float inv = 1.f / fmaxf((float)(end - beg), 1.f);
    half8 o;
    o[0] = (_Float16)(a0 * inv); o[1] = (_Float16)(a1 * inv);
    o[2] = (_Float16)(a2 * inv); o[3] = (_Float16)(a3 * inv);
    o[4] = (_Float16)(a4 * inv); o[5] = (_Float16)(a5 * inv);
    o[6] = (_Float16)(a6 * inv); o[7] = (_Float16)(a7 * inv);
    *(half8*)(ab + (batch * 4 + g) * 136 + j * 8) = o;
  }
}

// ---------------- layer-1: h1 = relu([mean_agg(X) | X] @ Wp1 + b1) ----------------
// 1 wave per block, 16 rows. A-frag: lane holds A[m=lane&15][kt*32+(lane>>4)*8+j];
// D: col=lane&15, row=(lane>>4)*4+reg (guide m89/m91). All LDS deps wave-internal.
__global__ __launch_bounds__(64) void gemm1_k(const _Float16* __restrict__ X,
                                              const int* __restrict__ row_off,
                                              const int* __restrict__ csr,
                                              const _Float16* __restrict__ Bp,
                                              const float* __restrict__ bias,
                                              _Float16* __restrict__ Out, int M) {
  __shared__ _Float16 ab[16 * 136];
  int lane = threadIdx.x & 63;
  int row0 = blockIdx.x * 16;
  agg_to_lds(X, row_off, csr, ab, row0, M, lane);
  int m = lane & 15, quad = lane >> 4;
  int arow = row0 + m; if (arow > M - 1) arow = M - 1;
  f32x4 acc[8];
#pragma unroll
  for (int i = 0; i < 8; ++i) acc[i] = (f32x4){0.f, 0.f, 0.f, 0.f};
#pragma unroll
  for (int kt = 0; kt < 8; ++kt) {
    half8 af = (kt < 4) ? *(const half8*)(ab + m * 136 + kt * 32 + quad * 8)
                        : *(const half8*)(X + (long)arow * 128 + (kt - 4) * 32 + quad * 8);
#pragma unroll
    for (int nt = 0; nt < 8; ++nt) {
      half8 bf = *(const half8*)(Bp + ((long)(kt * 8 + nt) * 64 + lane) * 8);
      acc[nt] = __builtin_amdgcn_mfma_f32_16x16x32_f16(af, bf, acc[nt], 0, 0, 0);
    }
  }
#pragma unroll
  for (int nt = 0; nt < 8; ++nt) {
    float bv = bias[nt * 16 + m];
#pragma unroll
    for (int r = 0; r < 4; ++r) {
      int orow = row0 + quad * 4 + r;
      if (orow < M)
        Out[(long)orow * 128 + nt * 16 + m] = (_Float16)fmaxf(acc[nt][r] + bv, 0.f);
    }
  }
}

// ---------------- layer-2 + classifier: out = ([mean_agg(h1)|h1]@Wp2 + b2) @ Wc + bc ----
// h2 tile stays on-chip: acc -> +b2 -> reuse same LDS tile -> A-frags -> @Wpc -> fp32 out.
__global__ __launch_bounds__(64) void gemm2cls_k(const _Float16* __restrict__ H1,
                                                 const int* __restrict__ row_off,
                                                 const int* __restrict__ csr,
                                                 const _Float16* __restrict__ Bp,
                                                 const float* __restrict__ bias,
                                                 const _Float16* __restrict__ Bpc,
                                                 const float* __restrict__ bc,
                                                 float* __restrict__ out, int M) {
  __shared__ _Float16 ab[16 * 136];
  int lane = threadIdx.x & 63;
  int row0 = blockIdx.x * 16;
  agg_to_lds(H1, row_off, csr, ab, row0, M, lane);
  int m = lane & 15, quad = lane >> 4;
  int arow = row0 + m; if (arow > M - 1) arow = M - 1;
  f32x4 acc[8];
#pragma unroll
  for (int i = 0; i < 8; ++i) acc[i] = (f32x4){0.f, 0.f, 0.f, 0.f};
#pragma unroll
  for (int kt = 0; kt < 8; ++kt) {
    half8 af = (kt < 4) ? *(const half8*)(ab + m * 136 + kt * 32 + quad * 8)
                        : *(const half8*)(H1 + (long)arow * 128 + (kt - 4) * 32 + quad * 8);
#pragma unroll
    for (int nt = 0; nt < 8; ++nt) {
      half8 bf = *(const half8*)(Bp + ((long)(kt * 8 + nt) * 64 + lane) * 8);
      acc[nt] = __builtin_amdgcn_mfma_f32_16x16x32_f16(af, bf, acc[nt], 0, 0, 0);
    }
  }
  // stage h2 back into the same wave-private tile (K-loop reads are complete in-order)
#pragma unroll
  for (int nt = 0; nt < 8; ++nt) {
    float bv = bias[nt * 16 + m];
#pragma unroll
    for (int r = 0; r < 4; ++r)
      ab[(quad * 4 + r) * 136 + nt * 16 + m] = (_Float16)(acc[nt][r] + bv);
  }
  f32x4 c2 = (f32x4){0.f, 0.f, 0.f, 0.f};
#pragma unroll
  for (int kt = 0; kt < 4; ++kt) {
    half8 af = *(const half8*)(ab + m * 136 + kt * 32 + quad * 8);
    half8 bf = *(const half8*)(Bpc + ((long)(kt * 64 + lane)) * 8);
    c2 = __builtin_amdgcn_mfma_f32_16x16x32_f16(af, bf, c2, 0, 0, 0);
  }
#pragma unroll
  for (int r = 0; r < 4; ++r) {
    int orow = row0 + quad * 4 + r;
    if (orow < M) out[(long)orow * 16 + m] = c2[r] + bc[m];
  }
}

extern "C" void kernel_launch(void* const* d_in, const int* in_sizes, int n_in,
                              void* d_out, int out_size, void* d_ws, size_t ws_size,
                              hipStream_t stream) {
  const int N = in_sizes[0];
  const int E = in_sizes[1] / 2;
  const int*   entity = (const int*)d_in[0];
  const int*   e_src  = (const int*)d_in[1];
  const int*   e_dst  = e_src + E;
  const float* emb    = (const float*)d_in[2];
  const float* W1l    = (const float*)d_in[3];
  const float* b1     = (const float*)d_in[4];
  const float* W1r    = (const float*)d_in[5];
  const float* W2l    = (const float*)d_in[6];
  const float* b2     = (const float*)d_in[7];
  const float* W2r    = (const float*)d_in[8];
  const float* Wc     = (const float*)d_in[9];
  const float* bc     = (const float*)d_in[10];
  float* out = (float*)d_out;

  // workspace layout
  char* p = (char*)d_ws;
  _Float16* x0  = (_Float16*)p; p += (size_t)N * 128 * 2;
  _Float16* h1  = (_Float16*)p; p += (size_t)N * 128 * 2;
  _Float16* Wp1 = (_Float16*)p; p += 256 * 128 * 2;
  _Float16* Wp2 = (_Float16*)p; p += 256 * 128 * 2;
  _Float16* Wpc = (_Float16*)p; p += 128 * 16 * 2;
  int* deg     = (int*)p; p += (size_t)N * 4;
  int* cur     = (int*)p; p += (size_t)N * 4;               // adjacent to deg: one memset
  int* row_off = (int*)p; p += (size_t)(N + 1) * 4;
  int* csr     = (int*)p; p += (size_t)E * 4;
  int* part    = (int*)p; p += 1024 * 4;

  const int NB = (N + 255) / 256;          // 196
  const int FB = (E + 255) / 256;          // 2344
  const int GB = (N * 16 + 255) / 256;     // 3125

  hipMemsetAsync(deg, 0, (size_t)N * 8, stream);            // zeros deg + cur

  count_deg_k<<<FB, 256, 0, stream>>>(e_dst, deg, E);
  deg_part_k<<<NB, 256, 0, stream>>>(deg, part, N);
  row_off_k<<<NB, 256, 0, stream>>>(deg, part, row_off, N, NB);
  build_k<<<FB + GB + 33, 256, 0, stream>>>(e_src, e_dst, row_off, cur, csr,
                                            entity, emb, x0,
                                            W1l, W1r, Wp1, W2l, W2r, Wp2, Wc, Wpc,
                                            N, E, FB, GB);

  int gblk = (N + 15) / 16;                // 3125, 1 wave / 16 rows per block
  // layer 1 (agg fused): h1 = relu([mean_agg(x0)|x0] @ Wp1 + b1)
  gemm1_k<<<gblk, 64, 0, stream>>>(x0, row_off, csr, Wp1, b1, h1, N);
  // layer 2 + classifier (agg fused): out = ([mean_agg(h1)|h1] @ Wp2 + b2) @ Wc + bc
  gemm2cls_k<<<gblk, 64, 0, stream>>>(h1, row_off, csr, Wp2, b2, Wpc, bc, out, N);
}

// Round 6
// 228.800 us; speedup vs baseline: 1.4654x; 1.0012x over previous
//
#include <hip/hip_runtime.h>

typedef _Float16 half8  __attribute__((ext_vector_type(8)));
typedef float    f32x4  __attribute__((ext_vector_type(4)));

// ---------------- CSR build ----------------
__global__ void count_deg_k(const int* __restrict__ dst, int* __restrict__ deg, int E) {
  int t = blockIdx.x * 256 + threadIdx.x;
  if (t < E) atomicAdd(&deg[dst[t]], 1);
}

// per-256-chunk partial sums (shuffle reduce, wave=64)
__global__ void deg_part_k(const int* __restrict__ deg, int* __restrict__ part, int N) {
  int t = blockIdx.x * 256 + threadIdx.x;
  int v = (t < N) ? deg[t] : 0;
  v += __shfl_down(v, 32); v += __shfl_down(v, 16); v += __shfl_down(v, 8);
  v += __shfl_down(v, 4);  v += __shfl_down(v, 2);  v += __shfl_down(v, 1);
  __shared__ int sm[4];
  if ((threadIdx.x & 63) == 0) sm[threadIdx.x >> 6] = v;
  __syncthreads();
  if (threadIdx.x == 0) part[blockIdx.x] = sm[0] + sm[1] + sm[2] + sm[3];
}

// row_off: every block scans the NB partials itself (LDS), then scans its own chunk.
__global__ void row_off_k(const int* __restrict__ deg, const int* __restrict__ part,
                          int* __restrict__ row_off, int N, int NB) {
  __shared__ int ps[256];
  __shared__ int sm[256];
  int tl = threadIdx.x;
  int pv = (tl < NB) ? part[tl] : 0;
  ps[tl] = pv; __syncthreads();
  for (int off = 1; off < 256; off <<= 1) {
    int a = ps[tl]; int b = (tl >= off) ? ps[tl - off] : 0;
    __syncthreads(); ps[tl] = a + b; __syncthreads();
  }
  int chunk_off = (blockIdx.x > 0) ? ps[blockIdx.x - 1] : 0;
  if (blockIdx.x == 0 && tl == 255) row_off[N] = ps[255];   // grand total
  int t = blockIdx.x * 256 + tl;
  int v = (t < N) ? deg[t] : 0;
  sm[tl] = v; __syncthreads();
  for (int off = 1; off < 256; off <<= 1) {
    int a = sm[tl]; int b = (tl >= off) ? sm[tl - off] : 0;
    __syncthreads(); sm[tl] = a + b; __syncthreads();
  }
  if (t < N) row_off[t] = chunk_off + sm[tl] - v;
}

// ---------------- fused build: CSR fill + embedding gather + weight packs ----------------
// B-frag order: lane holds B[kt*32+(lane>>4)*8+j][nt*16+(lane&15)], j=0..7, 16B contiguous.
__device__ __forceinline__ void pack_dev(const float* Wa, const float* Wb,
                                         _Float16* out, int NT, int ncols, int t) {
  int lane = t & 63, tile = t >> 6;
  int nt = tile % NT, kt = tile / NT;
  int n  = nt * 16 + (lane & 15);
  int kb = kt * 32 + (lane >> 4) * 8;
  half8 o;
#pragma unroll
  for (int j = 0; j < 8; ++j) {
    int k = kb + j;
    float w = (k < 128) ? Wa[k * ncols + n] : Wb[(k - 128) * ncols + n];
    o[j] = (_Float16)w;
  }
  *(half8*)(out + (long)t * 8) = o;
}

__global__ void build_k(const int* __restrict__ src, const int* __restrict__ dst,
                        const int* __restrict__ row_off, int* __restrict__ cur,
                        int* __restrict__ csr,
                        const int* __restrict__ ent, const float* __restrict__ emb,
                        _Float16* __restrict__ X,
                        const float* __restrict__ W1l, const float* __restrict__ W1r, _Float16* __restrict__ Wp1,
                        const float* __restrict__ W2l, const float* __restrict__ W2r, _Float16* __restrict__ Wp2,
                        const float* __restrict__ Wc, _Float16* __restrict__ Wpc,
                        int N, int E, int FB, int GB) {
  int b = blockIdx.x;
  if (b < FB) {                                    // CSR fill
    int t = b * 256 + threadIdx.x;
    if (t < E) {
      int d = dst[t];
      int p = atomicAdd(&cur[d], 1);
      csr[row_off[d] + p] = src[t];
    }
  } else if (b < FB + GB) {                        // embedding gather -> f16
    int t = (b - FB) * 256 + threadIdx.x;
    if (t >= N * 16) return;
    int node = t >> 4, g = t & 15;
    const float4* s = (const float4*)(emb + (long)ent[node] * 128 + g * 8);
    float4 a = s[0], c = s[1];
    half8 o;
    o[0] = (_Float16)a.x; o[1] = (_Float16)a.y; o[2] = (_Float16)a.z; o[3] = (_Float16)a.w;
    o[4] = (_Float16)c.x; o[5] = (_Float16)c.y; o[6] = (_Float16)c.z; o[7] = (_Float16)c.w;
    *(half8*)(X + (long)t * 8) = o;
  } else if (b < FB + GB + 16) {
    pack_dev(W1l, W1r, Wp1, 8, 128, (b - FB - GB) * 256 + threadIdx.x);
  } else if (b < FB + GB + 32) {
    pack_dev(W2l, W2r, Wp2, 8, 128, (b - FB - GB - 16) * 256 + threadIdx.x);
  } else {
    pack_dev(Wc, Wc, Wpc, 1, 16, threadIdx.x);     // KT=4, NT=1
  }
}

// ---------------- wave-private gather+mean into LDS tile (16 rows x 128, stride 136) ----
// 16-lane group per node, 4 nodes per pass, 4 passes -> 16 rows. half8 (16B) loads.
// Packed f16 accumulation: 4x v_pk_add_f16 per edge-load (vs 16 f32 cvt+add).
__device__ __forceinline__ void agg_to_lds(const _Float16* __restrict__ X,
                                           const int* __restrict__ row_off,
                                           const int* __restrict__ csr,
                                           _Float16* ab, int row0, int M, int lane) {
  int g = lane >> 4, j = lane & 15;
#pragma unroll
  for (int batch = 0; batch < 4; ++batch) {
    int node = row0 + batch * 4 + g;
    int nc = (node < M) ? node : M - 1;
    int beg = row_off[nc], end = row_off[nc + 1];
    half8 acc = (half8)(_Float16)0.f;
#pragma unroll 8
    for (int e = beg; e < end; ++e) {
      half8 v = *(const half8*)(X + (long)csr[e] * 128 + j * 8);
      acc += v;
    }
    _Float16 inv = (_Float16)(1.f / fmaxf((float)(end - beg), 1.f));
    acc *= (half8)inv;
    *(half8*)(ab + (batch * 4 + g) * 136 + j * 8) = acc;
  }
}

// ---------------- layer-1: h1 = relu([mean_agg(X) | X] @ Wp1 + b1) ----------------
// 1 wave per block, 16 rows. A-frag: lane holds A[m=lane&15][kt*32+(lane>>4)*8+j];
// D: col=lane&15, row=(lane>>4)*4+reg (guide m89/m91). All LDS deps wave-internal.
__global__ __launch_bounds__(64) void gemm1_k(const _Float16* __restrict__ X,
                                              const int* __restrict__ row_off,
                                              const int* __restrict__ csr,
                                              const _Float16* __restrict__ Bp,
                                              const float* __restrict__ bias,
                                              _Float16* __restrict__ Out, int M) {
  __shared__ _Float16 ab[16 * 136];
  int lane = threadIdx.x & 63;
  int row0 = blockIdx.x * 16;
  agg_to_lds(X, row_off, csr, ab, row0, M, lane);
  int m = lane & 15, quad = lane >> 4;
  int arow = row0 + m; if (arow > M - 1) arow = M - 1;
  f32x4 acc[8];
#pragma unroll
  for (int i = 0; i < 8; ++i) acc[i] = (f32x4){0.f, 0.f, 0.f, 0.f};
#pragma unroll
  for (int kt = 0; kt < 8; ++kt) {
    half8 af = (kt < 4) ? *(const half8*)(ab + m * 136 + kt * 32 + quad * 8)
                        : *(const half8*)(X + (long)arow * 128 + (kt - 4) * 32 + quad * 8);
#pragma unroll
    for (int nt = 0; nt < 8; ++nt) {
      half8 bf = *(const half8*)(Bp + ((long)(kt * 8 + nt) * 64 + lane) * 8);
      acc[nt] = __builtin_amdgcn_mfma_f32_16x16x32_f16(af, bf, acc[nt], 0, 0, 0);
    }
  }
#pragma unroll
  for (int nt = 0; nt < 8; ++nt) {
    float bv = bias[nt * 16 + m];
#pragma unroll
    for (int r = 0; r < 4; ++r) {
      int orow = row0 + quad * 4 + r;
      if (orow < M)
        Out[(long)orow * 128 + nt * 16 + m] = (_Float16)fmaxf(acc[nt][r] + bv, 0.f);
    }
  }
}

// ---------------- layer-2 + classifier: out = ([mean_agg(h1)|h1]@Wp2 + b2) @ Wc + bc ----
// h2 tile stays on-chip: acc -> +b2 -> reuse same LDS tile -> A-frags -> @Wpc -> fp32 out.
__global__ __launch_bounds__(64) void gemm2cls_k(const _Float16* __restrict__ H1,
                                                 const int* __restrict__ row_off,
                                                 const int* __restrict__ csr,
                                                 const _Float16* __restrict__ Bp,
                                                 const float* __restrict__ bias,
                                                 const _Float16* __restrict__ Bpc,
                                                 const float* __restrict__ bc,
                                                 float* __restrict__ out, int M) {
  __shared__ _Float16 ab[16 * 136];
  int lane = threadIdx.x & 63;
  int row0 = blockIdx.x * 16;
  agg_to_lds(H1, row_off, csr, ab, row0, M, lane);
  int m = lane & 15, quad = lane >> 4;
  int arow = row0 + m; if (arow > M - 1) arow = M - 1;
  f32x4 acc[8];
#pragma unroll
  for (int i = 0; i < 8; ++i) acc[i] = (f32x4){0.f, 0.f, 0.f, 0.f};
#pragma unroll
  for (int kt = 0; kt < 8; ++kt) {
    half8 af = (kt < 4) ? *(const half8*)(ab + m * 136 + kt * 32 + quad * 8)
                        : *(const half8*)(H1 + (long)arow * 128 + (kt - 4) * 32 + quad * 8);
#pragma unroll
    for (int nt = 0; nt < 8; ++nt) {
      half8 bf = *(const half8*)(Bp + ((long)(kt * 8 + nt) * 64 + lane) * 8);
      acc[nt] = __builtin_amdgcn_mfma_f32_16x16x32_f16(af, bf, acc[nt], 0, 0, 0);
    }
  }
  // stage h2 back into the same wave-private tile (K-loop reads are complete in-order)
#pragma unroll
  for (int nt = 0; nt < 8; ++nt) {
    float bv = bias[nt * 16 + m];
#pragma unroll
    for (int r = 0; r < 4; ++r)
      ab[(quad * 4 + r) * 136 + nt * 16 + m] = (_Float16)(acc[nt][r] + bv);
  }
  f32x4 c2 = (f32x4){0.f, 0.f, 0.f, 0.f};
#pragma unroll
  for (int kt = 0; kt < 4; ++kt) {
    half8 af = *(const half8*)(ab + m * 136 + kt * 32 + quad * 8);
    half8 bf = *(const half8*)(Bpc + ((long)(kt * 64 + lane)) * 8);
    c2 = __builtin_amdgcn_mfma_f32_16x16x32_f16(af, bf, c2, 0, 0, 0);
  }
#pragma unroll
  for (int r = 0; r < 4; ++r) {
    int orow = row0 + quad * 4 + r;
    if (orow < M) out[(long)orow * 16 + m] = c2[r] + bc[m];
  }
}

extern "C" void kernel_launch(void* const* d_in, const int* in_sizes, int n_in,
                              void* d_out, int out_size, void* d_ws, size_t ws_size,
                              hipStream_t stream) {
  const int N = in_sizes[0];
  const int E = in_sizes[1] / 2;
  const int*   entity = (const int*)d_in[0];
  const int*   e_src  = (const int*)d_in[1];
  const int*   e_dst  = e_src + E;
  const float* emb    = (const float*)d_in[2];
  const float* W1l    = (const float*)d_in[3];
  const float* b1     = (const float*)d_in[4];
  const float* W1r    = (const float*)d_in[5];
  const float* W2l    = (const float*)d_in[6];
  const float* b2     = (const float*)d_in[7];
  const float* W2r    = (const float*)d_in[8];
  const float* Wc     = (const float*)d_in[9];
  const float* bc     = (const float*)d_in[10];
  float* out = (float*)d_out;

  // workspace layout
  char* p = (char*)d_ws;
  _Float16* x0  = (_Float16*)p; p += (size_t)N * 128 * 2;
  _Float16* h1  = (_Float16*)p; p += (size_t)N * 128 * 2;
  _Float16* Wp1 = (_Float16*)p; p += 256 * 128 * 2;
  _Float16* Wp2 = (_Float16*)p; p += 256 * 128 * 2;
  _Float16* Wpc = (_Float16*)p; p += 128 * 16 * 2;
  int* deg     = (int*)p; p += (size_t)N * 4;
  int* cur     = (int*)p; p += (size_t)N * 4;               // adjacent to deg: one memset
  int* row_off = (int*)p; p += (size_t)(N + 1) * 4;
  int* csr     = (int*)p; p += (size_t)E * 4;
  int* part    = (int*)p; p += 1024 * 4;

  const int NB = (N + 255) / 256;          // 196
  const int FB = (E + 255) / 256;          // 2344
  const int GB = (N * 16 + 255) / 256;     // 3125

  hipMemsetAsync(deg, 0, (size_t)N * 8, stream);            // zeros deg + cur

  count_deg_k<<<FB, 256, 0, stream>>>(e_dst, deg, E);
  deg_part_k<<<NB, 256, 0, stream>>>(deg, part, N);
  row_off_k<<<NB, 256, 0, stream>>>(deg, part, row_off, N, NB);
  build_k<<<FB + GB + 33, 256, 0, stream>>>(e_src, e_dst, row_off, cur, csr,
                                            entity, emb, x0,
                                            W1l, W1r, Wp1, W2l, W2r, Wp2, Wc, Wpc,
                                            N, E, FB, GB);

  int gblk = (N + 15) / 16;                // 3125, 1 wave / 16 rows per block
  // layer 1 (agg fused): h1 = relu([mean_agg(x0)|x0] @ Wp1 + b1)
  gemm1_k<<<gblk, 64, 0, stream>>>(x0, row_off, csr, Wp1, b1, h1, N);
  // layer 2 + classifier (agg fused): out = ([mean_agg(h1)|h1] @ Wp2 + b2) @ Wc + bc
  gemm2cls_k<<<gblk, 64, 0, stream>>>(h1, row_off, csr, Wp2, b2, Wpc, bc, out, N);
}

// Round 7
// 228.006 us; speedup vs baseline: 1.4705x; 1.0035x over previous
//
#include <hip/hip_runtime.h>

typedef _Float16 half8  __attribute__((ext_vector_type(8)));
typedef float    f32x4  __attribute__((ext_vector_type(4)));

// ---------------- CSR build ----------------
__global__ void count_deg_k(const int* __restrict__ dst, int* __restrict__ deg, int E) {
  int t = blockIdx.x * 256 + threadIdx.x;
  if (t < E) atomicAdd(&deg[dst[t]], 1);
}

// per-256-chunk partial sums (shuffle reduce, wave=64)
__global__ void deg_part_k(const int* __restrict__ deg, int* __restrict__ part, int N) {
  int t = blockIdx.x * 256 + threadIdx.x;
  int v = (t < N) ? deg[t] : 0;
  v += __shfl_down(v, 32); v += __shfl_down(v, 16); v += __shfl_down(v, 8);
  v += __shfl_down(v, 4);  v += __shfl_down(v, 2);  v += __shfl_down(v, 1);
  __shared__ int sm[4];
  if ((threadIdx.x & 63) == 0) sm[threadIdx.x >> 6] = v;
  __syncthreads();
  if (threadIdx.x == 0) part[blockIdx.x] = sm[0] + sm[1] + sm[2] + sm[3];
}

// row_off: every block scans the NB partials itself (LDS), then scans its own chunk.
__global__ void row_off_k(const int* __restrict__ deg, const int* __restrict__ part,
                          int* __restrict__ row_off, int N, int NB) {
  __shared__ int ps[256];
  __shared__ int sm[256];
  int tl = threadIdx.x;
  int pv = (tl < NB) ? part[tl] : 0;
  ps[tl] = pv; __syncthreads();
  for (int off = 1; off < 256; off <<= 1) {
    int a = ps[tl]; int b = (tl >= off) ? ps[tl - off] : 0;
    __syncthreads(); ps[tl] = a + b; __syncthreads();
  }
  int chunk_off = (blockIdx.x > 0) ? ps[blockIdx.x - 1] : 0;
  if (blockIdx.x == 0 && tl == 255) row_off[N] = ps[255];   // grand total
  int t = blockIdx.x * 256 + tl;
  int v = (t < N) ? deg[t] : 0;
  sm[tl] = v; __syncthreads();
  for (int off = 1; off < 256; off <<= 1) {
    int a = sm[tl]; int b = (tl >= off) ? sm[tl - off] : 0;
    __syncthreads(); sm[tl] = a + b; __syncthreads();
  }
  if (t < N) row_off[t] = chunk_off + sm[tl] - v;
}

// ---------------- fused build: CSR fill + embedding gather + weight packs ----------------
// B-frag order: lane holds B[kt*32+(lane>>4)*8+j][nt*16+(lane&15)], j=0..7, 16B contiguous.
__device__ __forceinline__ void pack_dev(const float* Wa, const float* Wb,
                                         _Float16* out, int NT, int ncols, int t) {
  int lane = t & 63, tile = t >> 6;
  int nt = tile % NT, kt = tile / NT;
  int n  = nt * 16 + (lane & 15);
  int kb = kt * 32 + (lane >> 4) * 8;
  half8 o;
#pragma unroll
  for (int j = 0; j < 8; ++j) {
    int k = kb + j;
    float w = (k < 128) ? Wa[k * ncols + n] : Wb[(k - 128) * ncols + n];
    o[j] = (_Float16)w;
  }
  *(half8*)(out + (long)t * 8) = o;
}

__global__ void build_k(const int* __restrict__ src, const int* __restrict__ dst,
                        const int* __restrict__ row_off, int* __restrict__ cur,
                        int* __restrict__ csr,
                        const int* __restrict__ ent, const float* __restrict__ emb,
                        _Float16* __restrict__ X,
                        const float* __restrict__ W1l, const float* __restrict__ W1r, _Float16* __restrict__ Wp1,
                        const float* __restrict__ W2l, const float* __restrict__ W2r, _Float16* __restrict__ Wp2,
                        const float* __restrict__ Wc, _Float16* __restrict__ Wpc,
                        int N, int E, int FB, int GB) {
  int b = blockIdx.x;
  if (b < FB) {                                    // CSR fill
    int t = b * 256 + threadIdx.x;
    if (t < E) {
      int d = dst[t];
      int p = atomicAdd(&cur[d], 1);
      csr[row_off[d] + p] = src[t];
    }
  } else if (b < FB + GB) {                        // embedding gather -> f16
    int t = (b - FB) * 256 + threadIdx.x;
    if (t >= N * 16) return;
    int node = t >> 4, g = t & 15;
    const float4* s = (const float4*)(emb + (long)ent[node] * 128 + g * 8);
    float4 a = s[0], c = s[1];
    half8 o;
    o[0] = (_Float16)a.x; o[1] = (_Float16)a.y; o[2] = (_Float16)a.z; o[3] = (_Float16)a.w;
    o[4] = (_Float16)c.x; o[5] = (_Float16)c.y; o[6] = (_Float16)c.z; o[7] = (_Float16)c.w;
    *(half8*)(X + (long)t * 8) = o;
  } else if (b < FB + GB + 16) {
    pack_dev(W1l, W1r, Wp1, 8, 128, (b - FB - GB) * 256 + threadIdx.x);
  } else if (b < FB + GB + 32) {
    pack_dev(W2l, W2r, Wp2, 8, 128, (b - FB - GB - 16) * 256 + threadIdx.x);
  } else {
    pack_dev(Wc, Wc, Wpc, 1, 16, threadIdx.x);     // KT=4, NT=1
  }
}

// ---------------- wave-private gather+mean into LDS tile (16 rows x 128, stride 136) ----
// 16-lane group per node, 4 nodes per pass, 4 passes -> 16 rows. half8 (16B) loads.
// Packed f16 accumulation (4x v_pk_add_f16 per edge-load).
__device__ __forceinline__ void agg_to_lds(const _Float16* __restrict__ X,
                                           const int* __restrict__ row_off,
                                           const int* __restrict__ csr,
                                           _Float16* ab, int row0, int M, int lane) {
  int g = lane >> 4, j = lane & 15;
#pragma unroll
  for (int batch = 0; batch < 4; ++batch) {
    int node = row0 + batch * 4 + g;
    int nc = (node < M) ? node : M - 1;
    int beg = row_off[nc], end = row_off[nc + 1];
    half8 acc = (half8)(_Float16)0.f;
#pragma unroll 8
    for (int e = beg; e < end; ++e) {
      half8 v = *(const half8*)(X + (long)csr[e] * 128 + j * 8);
      acc += v;
    }
    _Float16 inv = (_Float16)(1.f / fmaxf((float)(end - beg), 1.f));
    acc *= (half8)inv;
    *(half8*)(ab + (batch * 4 + g) * 136 + j * 8) = acc;
  }
}

// ---------------- layer-1: h1 = relu([mean_agg(X) | X] @ Wp1 + b1) ----------------
// 128-thread block = 2 waves = 2 independent 16-row tiles (wave-private LDS, no barrier).
// A-frag: lane holds A[m=lane&15][kt*32+(lane>>4)*8+j]; D: col=lane&15, row=(lane>>4)*4+reg.
__global__ __launch_bounds__(128) void gemm1_k(const _Float16* __restrict__ X,
                                               const int* __restrict__ row_off,
                                               const int* __restrict__ csr,
                                               const _Float16* __restrict__ Bp,
                                               const float* __restrict__ bias,
                                               _Float16* __restrict__ Out, int M) {
  __shared__ _Float16 abuf[2][16 * 136];
  int wave = threadIdx.x >> 6, lane = threadIdx.x & 63;
  _Float16* ab = abuf[wave];
  int row0 = blockIdx.x * 32 + wave * 16;
  agg_to_lds(X, row_off, csr, ab, row0, M, lane);
  int m = lane & 15, quad = lane >> 4;
  int arow = row0 + m; if (arow > M - 1) arow = M - 1;
  f32x4 acc[8];
#pragma unroll
  for (int i = 0; i < 8; ++i) acc[i] = (f32x4){0.f, 0.f, 0.f, 0.f};
#pragma unroll
  for (int kt = 0; kt < 8; ++kt) {
    half8 af = (kt < 4) ? *(const half8*)(ab + m * 136 + kt * 32 + quad * 8)
                        : *(const half8*)(X + (long)arow * 128 + (kt - 4) * 32 + quad * 8);
#pragma unroll
    for (int nt = 0; nt < 8; ++nt) {
      half8 bf = *(const half8*)(Bp + ((long)(kt * 8 + nt) * 64 + lane) * 8);
      acc[nt] = __builtin_amdgcn_mfma_f32_16x16x32_f16(af, bf, acc[nt], 0, 0, 0);
    }
  }
#pragma unroll
  for (int nt = 0; nt < 8; ++nt) {
    float bv = bias[nt * 16 + m];
#pragma unroll
    for (int r = 0; r < 4; ++r) {
      int orow = row0 + quad * 4 + r;
      if (orow < M)
        Out[(long)orow * 128 + nt * 16 + m] = (_Float16)fmaxf(acc[nt][r] + bv, 0.f);
    }
  }
}

// ---------------- layer-2 + classifier: out = ([mean_agg(h1)|h1]@Wp2 + b2) @ Wc + bc ----
// h2 tile stays on-chip: acc -> +b2 -> reuse same wave-private LDS tile -> @Wpc -> fp32 out.
__global__ __launch_bounds__(128) void gemm2cls_k(const _Float16* __restrict__ H1,
                                                  const int* __restrict__ row_off,
                                                  const int* __restrict__ csr,
                                                  const _Float16* __restrict__ Bp,
                                                  const float* __restrict__ bias,
                                                  const _Float16* __restrict__ Bpc,
                                                  const float* __restrict__ bc,
                                                  float* __restrict__ out, int M) {
  __shared__ _Float16 abuf[2][16 * 136];
  int wave = threadIdx.x >> 6, lane = threadIdx.x & 63;
  _Float16* ab = abuf[wave];
  int row0 = blockIdx.x * 32 + wave * 16;
  agg_to_lds(H1, row_off, csr, ab, row0, M, lane);
  int m = lane & 15, quad = lane >> 4;
  int arow = row0 + m; if (arow > M - 1) arow = M - 1;
  f32x4 acc[8];
#pragma unroll
  for (int i = 0; i < 8; ++i) acc[i] = (f32x4){0.f, 0.f, 0.f, 0.f};
#pragma unroll
  for (int kt = 0; kt < 8; ++kt) {
    half8 af = (kt < 4) ? *(const half8*)(ab + m * 136 + kt * 32 + quad * 8)
                        : *(const half8*)(H1 + (long)arow * 128 + (kt - 4) * 32 + quad * 8);
#pragma unroll
    for (int nt = 0; nt < 8; ++nt) {
      half8 bf = *(const half8*)(Bp + ((long)(kt * 8 + nt) * 64 + lane) * 8);
      acc[nt] = __builtin_amdgcn_mfma_f32_16x16x32_f16(af, bf, acc[nt], 0, 0, 0);
    }
  }
  // stage h2 back into the same wave-private tile (K-loop LDS reads complete in-order)
#pragma unroll
  for (int nt = 0; nt < 8; ++nt) {
    float bv = bias[nt * 16 + m];
#pragma unroll
    for (int r = 0; r < 4; ++r)
      ab[(quad * 4 + r) * 136 + nt * 16 + m] = (_Float16)(acc[nt][r] + bv);
  }
  f32x4 c2 = (f32x4){0.f, 0.f, 0.f, 0.f};
#pragma unroll
  for (int kt = 0; kt < 4; ++kt) {
    half8 af = *(const half8*)(ab + m * 136 + kt * 32 + quad * 8);
    half8 bf = *(const half8*)(Bpc + ((long)(kt * 64 + lane)) * 8);
    c2 = __builtin_amdgcn_mfma_f32_16x16x32_f16(af, bf, c2, 0, 0, 0);
  }
#pragma unroll
  for (int r = 0; r < 4; ++r) {
    int orow = row0 + quad * 4 + r;
    if (orow < M) out[(long)orow * 16 + m] = c2[r] + bc[m];
  }
}

extern "C" void kernel_launch(void* const* d_in, const int* in_sizes, int n_in,
                              void* d_out, int out_size, void* d_ws, size_t ws_size,
                              hipStream_t stream) {
  const int N = in_sizes[0];
  const int E = in_sizes[1] / 2;
  const int*   entity = (const int*)d_in[0];
  const int*   e_src  = (const int*)d_in[1];
  const int*   e_dst  = e_src + E;
  const float* emb    = (const float*)d_in[2];
  const float* W1l    = (const float*)d_in[3];
  const float* b1     = (const float*)d_in[4];
  const float* W1r    = (const float*)d_in[5];
  const float* W2l    = (const float*)d_in[6];
  const float* b2     = (const float*)d_in[7];
  const float* W2r    = (const float*)d_in[8];
  const float* Wc     = (const float*)d_in[9];
  const float* bc     = (const float*)d_in[10];
  float* out = (float*)d_out;

  // workspace layout
  char* p = (char*)d_ws;
  _Float16* x0  = (_Float16*)p; p += (size_t)N * 128 * 2;
  _Float16* h1  = (_Float16*)p; p += (size_t)N * 128 * 2;
  _Float16* Wp1 = (_Float16*)p; p += 256 * 128 * 2;
  _Float16* Wp2 = (_Float16*)p; p += 256 * 128 * 2;
  _Float16* Wpc = (_Float16*)p; p += 128 * 16 * 2;
  int* deg     = (int*)p; p += (size_t)N * 4;
  int* cur     = (int*)p; p += (size_t)N * 4;               // adjacent to deg: one memset
  int* row_off = (int*)p; p += (size_t)(N + 1) * 4;
  int* csr     = (int*)p; p += (size_t)E * 4;
  int* part    = (int*)p; p += 1024 * 4;

  const int NB = (N + 255) / 256;          // 196
  const int FB = (E + 255) / 256;          // 2344
  const int GB = (N * 16 + 255) / 256;     // 3125

  hipMemsetAsync(deg, 0, (size_t)N * 8, stream);            // zeros deg + cur

  count_deg_k<<<FB, 256, 0, stream>>>(e_dst, deg, E);
  deg_part_k<<<NB, 256, 0, stream>>>(deg, part, N);
  row_off_k<<<NB, 256, 0, stream>>>(deg, part, row_off, N, NB);
  build_k<<<FB + GB + 33, 256, 0, stream>>>(e_src, e_dst, row_off, cur, csr,
                                            entity, emb, x0,
                                            W1l, W1r, Wp1, W2l, W2r, Wp2, Wc, Wpc,
                                            N, E, FB, GB);

  int gblk = (N + 31) / 32;                // 1563 blocks, 2 waves / 32 rows per block
  // layer 1 (agg fused): h1 = relu([mean_agg(x0)|x0] @ Wp1 + b1)
  gemm1_k<<<gblk, 128, 0, stream>>>(x0, row_off, csr, Wp1, b1, h1, N);
  // layer 2 + classifier (agg fused): out = ([mean_agg(h1)|h1] @ Wp2 + b2) @ Wc + bc
  gemm2cls_k<<<gblk, 128, 0, stream>>>(h1, row_off, csr, Wp2, b2, Wpc, bc, out, N);
}